// Round 9
// baseline (181.593 us; speedup 1.0000x reference)
//
#include <hip/hip_runtime.h>
#include <hip/hip_bf16.h>
#include <math.h>

// Problem constants
#define BB 2
#define SS 2048
#define DD 512
#define MTOT 4096   // B*S

typedef __attribute__((ext_vector_type(8))) short sv8;   // 8 bf16
typedef __attribute__((ext_vector_type(4))) float f32x4;

// workspace layout (bytes)
static const size_t OFF_XB    = 0;               // bf16 x      [4096][512]   4 MB
static const size_t OFF_WT    = 4194304;         // bf16 Wt     [5][512][512] 2.5 MB ([q|k|vo|r|o], [n][k])
static const size_t OFF_BIAS  = 6815744;         // f32 bias    [2048]        8 KB (bq|bk|bvo|br)
static const size_t OFF_Y     = 6823936;         // bf16 Y      [4096][1536]  12 MB (q|k|sence)
static const size_t OFF_VT    = 19406848;        // bf16 V't    [2][512][2048] 4 MB (v' transposed)
static const size_t OFF_READ  = 23601152;        // bf16 read   [4096][512]   4 MB
static const size_t OFF_PP    = 27795456;        // bf16 P'     [64][64][128]  1 MB
static const size_t OFF_WVRAW = 28844032;        // bf16 Wv raw [512][512]    512 KB

static __device__ __forceinline__ float bf2f(short s) {
    unsigned u = ((unsigned)(unsigned short)s) << 16;
    return __builtin_bit_cast(float, u);
}
static __device__ __forceinline__ short f2bf(float f) {
    unsigned u = __builtin_bit_cast(unsigned, f);
    unsigned r = 0x7fffu + ((u >> 16) & 1u);
    u += r;
    return (short)(u >> 16);
}

// async global->LDS, 16B per lane; LDS dest is wave-uniform base (HW adds lane*16)
#define GLOAD_LDS16(gp, lp)                                                        \
    __builtin_amdgcn_global_load_lds(                                              \
        (const __attribute__((address_space(1))) unsigned*)(gp),                   \
        (__attribute__((address_space(3))) unsigned*)(lp), 16, 0, 0)

// ------------- prep: weights cast+transpose (z=0..4), cast_x + bias/bvo (z=5) -------------
// z order: 0=Wq,1=Wk,2=Wv(also raw cast to wvraw),3=Wr,4=Wo
__global__ __launch_bounds__(256) void prep_all(const float* __restrict__ x,
                                                const float* __restrict__ Wq,
                                                const float* __restrict__ Wk,
                                                const float* __restrict__ Wv,
                                                const float* __restrict__ Wr,
                                                const float* __restrict__ Wo,
                                                const float* __restrict__ bq,
                                                const float* __restrict__ bk,
                                                const float* __restrict__ bv,
                                                const float* __restrict__ br,
                                                const float* __restrict__ bo,
                                                short* __restrict__ xb,
                                                short* __restrict__ wt,
                                                short* __restrict__ wvraw,
                                                float* __restrict__ ball) {
    int z = blockIdx.z;
    int tid = threadIdx.x;
    if (z == 5) {
        int flat = blockIdx.y * 16 + blockIdx.x;  // 0..255
        if (flat == 0) {
            // bias concat: bq | bk | bvo | br, where bvo = bv@Wo + bo
#pragma unroll
            for (int it = 0; it < 8; ++it) {
                int i = it * 256 + tid;  // 0..2047
                int sel = i >> 9;
                if (sel == 2) {
                    int c = i - 1024;
                    float acc = bo[c];
                    for (int j = 0; j < 512; ++j)
                        acc += bv[j] * Wo[(size_t)j * 512 + c];
                    ball[i] = acc;
                } else {
                    const float* src = (sel == 0) ? bq : (sel == 1) ? bk : br;
                    ball[i] = src[i & 511];
                }
            }
        }
        // cast x -> bf16, grid-stride over 524288 float4s
        for (int i = flat * 256 + tid; i < MTOT * DD / 4; i += 256 * 256) {
            float4 v = ((const float4*)x)[i];
            short4 o;
            o.x = f2bf(v.x); o.y = f2bf(v.y); o.z = f2bf(v.z); o.w = f2bf(v.w);
            ((short4*)xb)[i] = o;
        }
        return;
    }
    __shared__ float tile[32][33];
    const float* W = (z == 0) ? Wq : (z == 1) ? Wk : (z == 2) ? Wv : (z == 3) ? Wr : Wo;
    int k0 = blockIdx.y * 32, n0 = blockIdx.x * 32;
    int tx = tid & 31, ty = tid >> 5;  // ty in 0..7
    for (int r = ty; r < 32; r += 8) {
        float val = W[(size_t)(k0 + r) * 512 + n0 + tx];
        tile[r][tx] = val;
        if (z == 2) wvraw[(size_t)(k0 + r) * 512 + n0 + tx] = f2bf(val);  // raw row-major cast
    }
    __syncthreads();
    short* o = wt + (size_t)z * 512 * 512;
    for (int r = ty; r < 32; r += 8)
        o[(size_t)(n0 + r) * 512 + k0 + tx] = f2bf(tile[tx][r]);
}

// ------------- bf16 MFMA GEMM, global_load_lds staging, linear LDS -------------
// A: [M][512] bf16, Bt: [N][512] bf16. 128x128 tile, BK=64.
// GEMM1==0: plain: Cout[row*ldc+col] = f2bf(acc + bias[col]) (LDS-staged coalesced store).
// GEMM1==1: fused [q|k|v'|r] output:
//   cols <1024 (q,k)    -> Y[row*1536 + col]
//   cols 1024..1535 (v') -> operand-swapped MFMA, transposed out to Vt[b][d][t]
//   cols >=1536 (r)      -> Y[row*1536 + col-512]
// GEMM1==2: plain, no bias (bias may be nullptr).
template <int GEMM1>
__global__ __launch_bounds__(256) void gemm_bt(const short* __restrict__ A,
                                               const short* __restrict__ Bt,
                                               const float* __restrict__ bias,
                                               short* __restrict__ Cout, int ldc,
                                               short* __restrict__ vt) {
    __shared__ __align__(16) short lbuf[2 * 128 * 64];  // lA | lB; reused as C-tile [128][128]
    short* lA = lbuf;
    short* lB = lbuf + 128 * 64;
    int tid = threadIdx.x;
    int mbase = blockIdx.y * 128;
    int nbase = blockIdx.x * 128;
    int lane = tid & 63, wave = tid >> 6;
    int wm = wave >> 1, wn = wave & 1;
    bool vswap = (GEMM1 == 1) && (nbase >= 1024) && (nbase < 1536);

    f32x4 acc[4][4] = {};

    int srow = (lane >> 3);        // 0..7 within 8-row chunk
    int scol = (lane & 7) * 8;     // element offset (16B)

    for (int k0 = 0; k0 < 512; k0 += 64) {
#pragma unroll
        for (int c = 0; c < 4; ++c) {
            int ch = wave * 4 + c;  // 0..15, wave-uniform
            int row = ch * 8 + srow;
            GLOAD_LDS16(A + (size_t)(mbase + row) * 512 + k0 + scol, &lA[ch * 512]);
            GLOAD_LDS16(Bt + (size_t)(nbase + row) * 512 + k0 + scol, &lB[ch * 512]);
        }
        __syncthreads();
#pragma unroll
        for (int kk = 0; kk < 2; ++kk) {
            int koff = kk * 32 + (lane >> 4) * 8;
            sv8 af[4], bfr[4];
#pragma unroll
            for (int m = 0; m < 4; ++m)
                af[m] = *(const sv8*)&lA[(wm * 64 + m * 16 + (lane & 15)) * 64 + koff];
#pragma unroll
            for (int n = 0; n < 4; ++n)
                bfr[n] = *(const sv8*)&lB[(wn * 64 + n * 16 + (lane & 15)) * 64 + koff];
            if (!vswap) {
#pragma unroll
                for (int m = 0; m < 4; ++m)
#pragma unroll
                    for (int n = 0; n < 4; ++n)
                        acc[m][n] = __builtin_amdgcn_mfma_f32_16x16x32_bf16(
                            af[m], bfr[n], acc[m][n], 0, 0, 0);
            } else {  // swapped: acc holds the transposed tile
#pragma unroll
                for (int m = 0; m < 4; ++m)
#pragma unroll
                    for (int n = 0; n < 4; ++n)
                        acc[m][n] = __builtin_amdgcn_mfma_f32_16x16x32_bf16(
                            bfr[n], af[m], acc[m][n], 0, 0, 0);
            }
        }
        __syncthreads();  // also guards lbuf reuse as C-tile below
    }

    int r0 = (lane >> 4) * 4, c0 = lane & 15;
    if (!vswap) {
        // stage C tile (bias added) into LDS, then 16B-coalesced global stores
        short* sC = lbuf;  // [128][128]
#pragma unroll
        for (int m = 0; m < 4; ++m)
#pragma unroll
            for (int n = 0; n < 4; ++n) {
                int cl = wn * 64 + n * 16 + c0;
                float bv = (GEMM1 == 2) ? 0.f : bias[nbase + cl];
#pragma unroll
                for (int j = 0; j < 4; ++j) {
                    int rl = wm * 64 + m * 16 + r0 + j;
                    sC[rl * 128 + cl] = f2bf(acc[m][n][j] + bv);
                }
            }
        __syncthreads();
        int nybase = (GEMM1 == 1 && nbase >= 1536) ? nbase - 512 : nbase;
#pragma unroll
        for (int it = 0; it < 8; ++it) {
            int idx = it * 256 + tid;          // 0..2047
            int row = idx >> 4, slot = idx & 15;
            sv8 v = *(const sv8*)&sC[row * 128 + slot * 8];
            *(sv8*)&Cout[(size_t)(mbase + row) * ldc + nybase + slot * 8] = v;
        }
    } else {
        // Vt[b][d][t]: frag rows -> d (feature), frag cols -> t (token, 16-lane contiguous)
        int bb = mbase >> 11, tb = mbase & 2047;
#pragma unroll
        for (int m = 0; m < 4; ++m)
#pragma unroll
            for (int n = 0; n < 4; ++n) {
                int dglob = nbase + wn * 64 + n * 16 + r0;   // bias index (v' cols)
                int d = dglob - 1024;
                int tl = tb + wm * 64 + m * 16 + c0;
#pragma unroll
                for (int j = 0; j < 4; ++j) {
                    float v = acc[m][n][j] + bias[dglob + j];
                    vt[((size_t)bb * 512 + d + j) * 2048 + tl] = f2bf(v);
                }
            }
    }
}

// ------------- attention scores + softmax -> band probs P' -------------
// q-tile of 64 queries; key window of 128: kr = t0-64+j. Y: [4096][1536] = [q|k|sence].
__global__ __launch_bounds__(256) void attn_scores(const short* __restrict__ Y,
                                                   short* __restrict__ Pp) {
    __shared__ float sS[64][132];
    int tile = blockIdx.x;  // 0..63
    int b = tile >> 5;
    int t0 = (tile & 31) * 64;
    int s0 = tile * 64;
    int tid = threadIdx.x, lane = tid & 63, wave = tid >> 6;
    int wm = wave >> 1, wn = wave & 1;

    f32x4 acc[2][4] = {};
    const short* Q = Y;
    const short* Kb = Y + 512;

    int arow[2], brow[4];
#pragma unroll
    for (int m = 0; m < 2; ++m) arow[m] = s0 + wm * 32 + m * 16 + (lane & 15);
#pragma unroll
    for (int n = 0; n < 4; ++n) {
        int kr = t0 - 64 + wn * 64 + n * 16 + (lane & 15);
        if (kr < 0) kr = 0;  // masked later
        brow[n] = (b << 11) + kr;
    }
#pragma unroll
    for (int step = 0; step < 16; ++step) {
        int koff = step * 32 + (lane >> 4) * 8;
        sv8 af[2], bfr[4];
#pragma unroll
        for (int m = 0; m < 2; ++m)
            af[m] = *(const sv8*)(Q + (size_t)arow[m] * 1536 + koff);
#pragma unroll
        for (int n = 0; n < 4; ++n)
            bfr[n] = *(const sv8*)(Kb + (size_t)brow[n] * 1536 + koff);
#pragma unroll
        for (int m = 0; m < 2; ++m)
#pragma unroll
            for (int n = 0; n < 4; ++n)
                acc[m][n] = __builtin_amdgcn_mfma_f32_16x16x32_bf16(
                    af[m], bfr[n], acc[m][n], 0, 0, 0);
    }
    int r0 = (lane >> 4) * 4, c0 = lane & 15;
#pragma unroll
    for (int m = 0; m < 2; ++m)
#pragma unroll
        for (int n = 0; n < 4; ++n) {
            int jc = wn * 64 + n * 16 + c0;
#pragma unroll
            for (int j = 0; j < 4; ++j)
                sS[wm * 32 + m * 16 + r0 + j][jc] =
                    acc[m][n][j] * 0.04419417382415922f;  // 1/sqrt(512)
        }
    __syncthreads();

    // softmax: thread -> (q = tid>>2, quarter = tid&3)
    int q = tid >> 2, j0 = (tid & 3) * 32;
    float v[32];
    float mx = -1e30f;
    int jlo = q + 1;
    int jmin0 = 64 - t0;
    if (jmin0 > jlo) jlo = jmin0;
    int jhi = q + 64;
#pragma unroll
    for (int jj = 0; jj < 32; ++jj) {
        int j = j0 + jj;
        bool ok = (j >= jlo) && (j <= jhi);
        float s = ok ? sS[q][j] : -1e30f;
        v[jj] = s;
        mx = fmaxf(mx, s);
    }
    mx = fmaxf(mx, __shfl_xor(mx, 1));
    mx = fmaxf(mx, __shfl_xor(mx, 2));
    float sum = 0.f;
#pragma unroll
    for (int jj = 0; jj < 32; ++jj) {
        float e = (v[jj] > -1e29f) ? __expf(v[jj] - mx) : 0.f;
        v[jj] = e;
        sum += e;
    }
    sum += __shfl_xor(sum, 1);
    sum += __shfl_xor(sum, 2);
    float inv = 1.f / sum;
    short* dst = Pp + (size_t)tile * 8192 + q * 128 + j0;
#pragma unroll
    for (int k = 0; k < 4; ++k) {
        sv8 o;
#pragma unroll
        for (int e = 0; e < 8; ++e) o[e] = f2bf(v[k * 8 + e] * inv);
        *(sv8*)(dst + k * 8) = o;
    }
}

// ------------- PV: read[64 x 128-chunk] = P'[64x128] @ V'[128 x d] via Vt -------------
__global__ __launch_bounds__(256) void attn_pv(const short* __restrict__ Pp,
                                               const short* __restrict__ Vt,
                                               short* __restrict__ readb) {
    int tile = blockIdx.y, dchunk = blockIdx.x;  // 64 tiles x 4 d-chunks of 128
    int b = tile >> 5;
    int t0 = (tile & 31) * 64;
    int s0 = tile * 64;
    int tid = threadIdx.x, lane = tid & 63, wave = tid >> 6;
    int wm = wave >> 1, wn = wave & 1;

    f32x4 acc[2][4] = {};
    const short* Pbase = Pp + (size_t)tile * 8192;
#pragma unroll
    for (int ks = 0; ks < 4; ++ks) {
        int koff = ks * 32 + (lane >> 4) * 8;
        sv8 af[2], bfr[4];
#pragma unroll
        for (int m = 0; m < 2; ++m)
            af[m] = *(const sv8*)(Pbase + (wm * 32 + m * 16 + (lane & 15)) * 128 + koff);
#pragma unroll
        for (int n = 0; n < 4; ++n) {
            int d = dchunk * 128 + wn * 64 + n * 16 + (lane & 15);
            long off = (long)(b * 512 + d) * 2048 + (t0 - 64 + koff);  // <0 only where P'=0
            bfr[n] = *(const sv8*)(Vt + off);
        }
#pragma unroll
        for (int m = 0; m < 2; ++m)
#pragma unroll
            for (int n = 0; n < 4; ++n)
                acc[m][n] = __builtin_amdgcn_mfma_f32_16x16x32_bf16(
                    af[m], bfr[n], acc[m][n], 0, 0, 0);
    }
    int r0 = (lane >> 4) * 4, c0 = lane & 15;
#pragma unroll
    for (int m = 0; m < 2; ++m)
#pragma unroll
        for (int n = 0; n < 4; ++n) {
            int col = dchunk * 128 + wn * 64 + n * 16 + c0;
#pragma unroll
            for (int j = 0; j < 4; ++j) {
                int row = s0 + wm * 32 + m * 16 + r0 + j;
                readb[(size_t)row * 512 + col] = f2bf(acc[m][n][j]);
            }
        }
}

// ------------- LN(read) + LN(sence) + GeLU: one wave per row, sv8 loads -------------
__global__ __launch_bounds__(256) void ln_gelu(const short* __restrict__ readb,
                                               const short* __restrict__ Y,
                                               const float* __restrict__ gamma,
                                               const float* __restrict__ beta,
                                               float* __restrict__ out) {
    int row = blockIdx.x * 4 + (threadIdx.x >> 6);  // 4 waves = 4 rows per block
    int lane = threadIdx.x & 63;
    sv8 rv = *(const sv8*)(readb + (size_t)row * 512 + lane * 8);
    sv8 sv = *(const sv8*)(Y + (size_t)row * 1536 + 1024 + lane * 8);
    float rf[8], sf[8];
    float sr = 0.f, sr2 = 0.f, ss = 0.f, ss2 = 0.f;
#pragma unroll
    for (int e = 0; e < 8; ++e) {
        rf[e] = bf2f(rv[e]); sf[e] = bf2f(sv[e]);
        sr += rf[e]; sr2 += rf[e] * rf[e];
        ss += sf[e]; ss2 += sf[e] * sf[e];
    }
#pragma unroll
    for (int off = 32; off; off >>= 1) {
        sr += __shfl_xor(sr, off);
        sr2 += __shfl_xor(sr2, off);
        ss += __shfl_xor(ss, off);
        ss2 += __shfl_xor(ss2, off);
    }
    float mu_r = sr * (1.f / 512.f);
    float is_r = rsqrtf(sr2 * (1.f / 512.f) - mu_r * mu_r + 1e-5f);
    float mu_s = ss * (1.f / 512.f);
    float is_s = rsqrtf(ss2 * (1.f / 512.f) - mu_s * mu_s + 1e-5f);

    float4 ga = ((const float4*)gamma)[lane * 2];
    float4 gb = ((const float4*)gamma)[lane * 2 + 1];
    float4 ba = ((const float4*)beta)[lane * 2];
    float4 bb = ((const float4*)beta)[lane * 2 + 1];
    float g[8] = {ga.x, ga.y, ga.z, ga.w, gb.x, gb.y, gb.z, gb.w};
    float be[8] = {ba.x, ba.y, ba.z, ba.w, bb.x, bb.y, bb.z, bb.w};

    float y[8];
#pragma unroll
    for (int e = 0; e < 8; ++e) {
        float xv = (rf[e] - mu_r) * is_r * g[e] + be[e] +
                   (sf[e] - mu_s) * is_s * g[e] + be[e];
        y[e] = 0.5f * xv * (1.f + erff(xv * 0.70710678118654752f));
    }
    float* o = out + (size_t)row * 512 + lane * 8;
    ((float4*)o)[0] = make_float4(y[0], y[1], y[2], y[3]);
    ((float4*)o)[1] = make_float4(y[4], y[5], y[6], y[7]);
}

extern "C" void kernel_launch(void* const* d_in, const int* in_sizes, int n_in,
                              void* d_out, int out_size, void* d_ws, size_t ws_size,
                              hipStream_t stream) {
    const float* x  = (const float*)d_in[0];
    const float* Wq = (const float*)d_in[1];
    const float* bq = (const float*)d_in[2];
    const float* Wk = (const float*)d_in[3];
    const float* bk = (const float*)d_in[4];
    const float* Wv = (const float*)d_in[5];
    const float* bv = (const float*)d_in[6];
    const float* Wo = (const float*)d_in[7];
    const float* bo = (const float*)d_in[8];
    const float* Wr = (const float*)d_in[9];
    const float* br = (const float*)d_in[10];
    const float* gamma = (const float*)d_in[11];
    const float* beta  = (const float*)d_in[12];

    char* ws = (char*)d_ws;
    short* xb    = (short*)(ws + OFF_XB);
    short* wt    = (short*)(ws + OFF_WT);
    float* ball  = (float*)(ws + OFF_BIAS);
    short* Y     = (short*)(ws + OFF_Y);
    short* vtb   = (short*)(ws + OFF_VT);
    short* readb = (short*)(ws + OFF_READ);
    short* Pp    = (short*)(ws + OFF_PP);
    short* wvraw = (short*)(ws + OFF_WVRAW);

    prep_all<<<dim3(16, 16, 6), 256, 0, stream>>>(x, Wq, Wk, Wv, Wr, Wo,
                                                  bq, bk, bv, br, bo, xb, wt, wvraw, ball);

    // Wvo^T = (Wv@Wo)^T into wt slot 2: C[m][n] = Wo^T[m][:] . Wv[n][:] = Wvo[n][m]
    gemm_bt<2><<<dim3(4, 4), 256, 0, stream>>>(wt + (size_t)4 * 512 * 512, wvraw,
                                               nullptr, wt + (size_t)2 * 512 * 512,
                                               512, nullptr);

    // one launch: Y=[q|k|sence] plus V't (v' cols, transposed via operand swap)
    gemm_bt<1><<<dim3(16, 32), 256, 0, stream>>>(xb, wt, ball, Y, 1536, vtb);

    attn_scores<<<64, 256, 0, stream>>>(Y, Pp);
    attn_pv<<<dim3(4, 64), 256, 0, stream>>>(Pp, vtb, readb);  // = read directly

    ln_gelu<<<1024, 256, 0, stream>>>(readb, Y, gamma, beta, (float*)d_out);
}

// Round 10
// 166.553 us; speedup vs baseline: 1.0903x; 1.0903x over previous
//
#include <hip/hip_runtime.h>
#include <hip/hip_bf16.h>
#include <math.h>

// Problem constants
#define BB 2
#define SS 2048
#define DD 512
#define MTOT 4096   // B*S

typedef __attribute__((ext_vector_type(8))) short sv8;   // 8 bf16
typedef __attribute__((ext_vector_type(4))) float f32x4;

// workspace layout (bytes)
static const size_t OFF_XB    = 0;               // bf16 x      [4096][512]   4 MB
static const size_t OFF_WT    = 4194304;         // bf16 Wt     [5][512][512] 2.5 MB ([q|k|vo|r|o], [n][k])
static const size_t OFF_BIAS  = 6815744;         // f32 bias    [2048]        8 KB (bq|bk|bvo|br)
static const size_t OFF_Y     = 6823936;         // bf16 Y      [4096][1536]  12 MB (q|k|sence)
static const size_t OFF_VT    = 19406848;        // bf16 V't    [2][512][2048] 4 MB (v' transposed)
static const size_t OFF_READ  = 23601152;        // bf16 read   [4096][512]   4 MB
static const size_t OFF_PP    = 27795456;        // bf16 P'     [64][64][128]  1 MB
static const size_t OFF_WVRAW = 28844032;        // bf16 Wv raw [512][512]    512 KB

static __device__ __forceinline__ float bf2f(short s) {
    unsigned u = ((unsigned)(unsigned short)s) << 16;
    return __builtin_bit_cast(float, u);
}
static __device__ __forceinline__ short f2bf(float f) {
    unsigned u = __builtin_bit_cast(unsigned, f);
    unsigned r = 0x7fffu + ((u >> 16) & 1u);
    u += r;
    return (short)(u >> 16);
}

// async global->LDS, 16B per lane; LDS dest is wave-uniform base (HW adds lane*16)
#define GLOAD_LDS16(gp, lp)                                                        \
    __builtin_amdgcn_global_load_lds(                                              \
        (const __attribute__((address_space(1))) unsigned*)(gp),                   \
        (__attribute__((address_space(3))) unsigned*)(lp), 16, 0, 0)

// ------------- prep: weights cast+transpose (z=0..4), cast_x + bias/bvo (z=5) -------------
// z order: 0=Wq,1=Wk,2=Wv(also raw cast to wvraw),3=Wr,4=Wo
__global__ __launch_bounds__(256) void prep_all(const float* __restrict__ x,
                                                const float* __restrict__ Wq,
                                                const float* __restrict__ Wk,
                                                const float* __restrict__ Wv,
                                                const float* __restrict__ Wr,
                                                const float* __restrict__ Wo,
                                                const float* __restrict__ bq,
                                                const float* __restrict__ bk,
                                                const float* __restrict__ bv,
                                                const float* __restrict__ br,
                                                const float* __restrict__ bo,
                                                short* __restrict__ xb,
                                                short* __restrict__ wt,
                                                short* __restrict__ wvraw,
                                                float* __restrict__ ball) {
    int z = blockIdx.z;
    int tid = threadIdx.x;
    if (z == 5) {
        int flat = blockIdx.y * 16 + blockIdx.x;  // 0..255
        // bias concat spread over 8 blocks: bq | bk | bvo | br, bvo = bv@Wo + bo
        if (flat < 8) {
            int i = flat * 256 + tid;  // 0..2047
            int sel = i >> 9;
            if (sel == 2) {
                int c = i - 1024;
                // ILP-pipelined reduction: 8 independent partial sums
                float p0 = 0.f, p1 = 0.f, p2 = 0.f, p3 = 0.f;
                float p4 = 0.f, p5 = 0.f, p6 = 0.f, p7 = 0.f;
                for (int j0 = 0; j0 < 512; j0 += 8) {
                    p0 += bv[j0 + 0] * Wo[(size_t)(j0 + 0) * 512 + c];
                    p1 += bv[j0 + 1] * Wo[(size_t)(j0 + 1) * 512 + c];
                    p2 += bv[j0 + 2] * Wo[(size_t)(j0 + 2) * 512 + c];
                    p3 += bv[j0 + 3] * Wo[(size_t)(j0 + 3) * 512 + c];
                    p4 += bv[j0 + 4] * Wo[(size_t)(j0 + 4) * 512 + c];
                    p5 += bv[j0 + 5] * Wo[(size_t)(j0 + 5) * 512 + c];
                    p6 += bv[j0 + 6] * Wo[(size_t)(j0 + 6) * 512 + c];
                    p7 += bv[j0 + 7] * Wo[(size_t)(j0 + 7) * 512 + c];
                }
                ball[i] = bo[c] + (((p0 + p1) + (p2 + p3)) + ((p4 + p5) + (p6 + p7)));
            } else {
                const float* src = (sel == 0) ? bq : (sel == 1) ? bk : br;
                ball[i] = src[i & 511];
            }
        }
        // cast x -> bf16, grid-stride over 524288 float4s
        for (int i = flat * 256 + tid; i < MTOT * DD / 4; i += 256 * 256) {
            float4 v = ((const float4*)x)[i];
            short4 o;
            o.x = f2bf(v.x); o.y = f2bf(v.y); o.z = f2bf(v.z); o.w = f2bf(v.w);
            ((short4*)xb)[i] = o;
        }
        return;
    }
    __shared__ float tile[32][33];
    const float* W = (z == 0) ? Wq : (z == 1) ? Wk : (z == 2) ? Wv : (z == 3) ? Wr : Wo;
    int k0 = blockIdx.y * 32, n0 = blockIdx.x * 32;
    int tx = tid & 31, ty = tid >> 5;  // ty in 0..7
    for (int r = ty; r < 32; r += 8) {
        float val = W[(size_t)(k0 + r) * 512 + n0 + tx];
        tile[r][tx] = val;
        if (z == 2) wvraw[(size_t)(k0 + r) * 512 + n0 + tx] = f2bf(val);  // raw row-major cast
    }
    __syncthreads();
    short* o = wt + (size_t)z * 512 * 512;
    for (int r = ty; r < 32; r += 8)
        o[(size_t)(n0 + r) * 512 + k0 + tx] = f2bf(tile[tx][r]);
}

// ------------- bf16 MFMA GEMM, global_load_lds staging, linear LDS -------------
// A: [M][512] bf16, Bt: [N][512] bf16. 128x128 tile, BK=64.
// GEMM1==0: plain: Cout[row*ldc+col] = f2bf(acc + bias[col]) (LDS-staged coalesced store).
// GEMM1==1: fused [q|k|v'|r] output:
//   cols <1024 (q,k)    -> Y[row*1536 + col]
//   cols 1024..1535 (v') -> operand-swapped MFMA, transposed out to Vt[b][d][t]
//   cols >=1536 (r)      -> Y[row*1536 + col-512]
// GEMM1==2: plain, no bias (bias may be nullptr).
template <int GEMM1>
__global__ __launch_bounds__(256) void gemm_bt(const short* __restrict__ A,
                                               const short* __restrict__ Bt,
                                               const float* __restrict__ bias,
                                               short* __restrict__ Cout, int ldc,
                                               short* __restrict__ vt) {
    __shared__ __align__(16) short lbuf[2 * 128 * 64];  // lA | lB; reused as C-tile [128][128]
    short* lA = lbuf;
    short* lB = lbuf + 128 * 64;
    int tid = threadIdx.x;
    int mbase = blockIdx.y * 128;
    int nbase = blockIdx.x * 128;
    int lane = tid & 63, wave = tid >> 6;
    int wm = wave >> 1, wn = wave & 1;
    bool vswap = (GEMM1 == 1) && (nbase >= 1024) && (nbase < 1536);

    f32x4 acc[4][4] = {};

    int srow = (lane >> 3);        // 0..7 within 8-row chunk
    int scol = (lane & 7) * 8;     // element offset (16B)

    for (int k0 = 0; k0 < 512; k0 += 64) {
#pragma unroll
        for (int c = 0; c < 4; ++c) {
            int ch = wave * 4 + c;  // 0..15, wave-uniform
            int row = ch * 8 + srow;
            GLOAD_LDS16(A + (size_t)(mbase + row) * 512 + k0 + scol, &lA[ch * 512]);
            GLOAD_LDS16(Bt + (size_t)(nbase + row) * 512 + k0 + scol, &lB[ch * 512]);
        }
        __syncthreads();
#pragma unroll
        for (int kk = 0; kk < 2; ++kk) {
            int koff = kk * 32 + (lane >> 4) * 8;
            sv8 af[4], bfr[4];
#pragma unroll
            for (int m = 0; m < 4; ++m)
                af[m] = *(const sv8*)&lA[(wm * 64 + m * 16 + (lane & 15)) * 64 + koff];
#pragma unroll
            for (int n = 0; n < 4; ++n)
                bfr[n] = *(const sv8*)&lB[(wn * 64 + n * 16 + (lane & 15)) * 64 + koff];
            if (!vswap) {
#pragma unroll
                for (int m = 0; m < 4; ++m)
#pragma unroll
                    for (int n = 0; n < 4; ++n)
                        acc[m][n] = __builtin_amdgcn_mfma_f32_16x16x32_bf16(
                            af[m], bfr[n], acc[m][n], 0, 0, 0);
            } else {  // swapped: acc holds the transposed tile
#pragma unroll
                for (int m = 0; m < 4; ++m)
#pragma unroll
                    for (int n = 0; n < 4; ++n)
                        acc[m][n] = __builtin_amdgcn_mfma_f32_16x16x32_bf16(
                            bfr[n], af[m], acc[m][n], 0, 0, 0);
            }
        }
        __syncthreads();  // also guards lbuf reuse as C-tile below
    }

    int r0 = (lane >> 4) * 4, c0 = lane & 15;
    if (!vswap) {
        // stage C tile (bias added) into LDS, then 16B-coalesced global stores
        short* sC = lbuf;  // [128][128]
#pragma unroll
        for (int m = 0; m < 4; ++m)
#pragma unroll
            for (int n = 0; n < 4; ++n) {
                int cl = wn * 64 + n * 16 + c0;
                float bv = (GEMM1 == 2) ? 0.f : bias[nbase + cl];
#pragma unroll
                for (int j = 0; j < 4; ++j) {
                    int rl = wm * 64 + m * 16 + r0 + j;
                    sC[rl * 128 + cl] = f2bf(acc[m][n][j] + bv);
                }
            }
        __syncthreads();
        int nybase = (GEMM1 == 1 && nbase >= 1536) ? nbase - 512 : nbase;
#pragma unroll
        for (int it = 0; it < 8; ++it) {
            int idx = it * 256 + tid;          // 0..2047
            int row = idx >> 4, slot = idx & 15;
            sv8 v = *(const sv8*)&sC[row * 128 + slot * 8];
            *(sv8*)&Cout[(size_t)(mbase + row) * ldc + nybase + slot * 8] = v;
        }
    } else {
        // Vt[b][d][t]: frag rows -> d (feature), frag cols -> t (token, 16-lane contiguous)
        int bb = mbase >> 11, tb = mbase & 2047;
#pragma unroll
        for (int m = 0; m < 4; ++m)
#pragma unroll
            for (int n = 0; n < 4; ++n) {
                int dglob = nbase + wn * 64 + n * 16 + r0;   // bias index (v' cols)
                int d = dglob - 1024;
                int tl = tb + wm * 64 + m * 16 + c0;
#pragma unroll
                for (int j = 0; j < 4; ++j) {
                    float v = acc[m][n][j] + bias[dglob + j];
                    vt[((size_t)bb * 512 + d + j) * 2048 + tl] = f2bf(v);
                }
            }
    }
}

// ------------- attention scores + softmax -> band probs P' -------------
// q-tile of 64 queries; key window of 128: kr = t0-64+j. Y: [4096][1536] = [q|k|sence].
__global__ __launch_bounds__(256) void attn_scores(const short* __restrict__ Y,
                                                   short* __restrict__ Pp) {
    __shared__ float sS[64][132];
    int tile = blockIdx.x;  // 0..63
    int b = tile >> 5;
    int t0 = (tile & 31) * 64;
    int s0 = tile * 64;
    int tid = threadIdx.x, lane = tid & 63, wave = tid >> 6;
    int wm = wave >> 1, wn = wave & 1;

    f32x4 acc[2][4] = {};
    const short* Q = Y;
    const short* Kb = Y + 512;

    int arow[2], brow[4];
#pragma unroll
    for (int m = 0; m < 2; ++m) arow[m] = s0 + wm * 32 + m * 16 + (lane & 15);
#pragma unroll
    for (int n = 0; n < 4; ++n) {
        int kr = t0 - 64 + wn * 64 + n * 16 + (lane & 15);
        if (kr < 0) kr = 0;  // masked later
        brow[n] = (b << 11) + kr;
    }
#pragma unroll
    for (int step = 0; step < 16; ++step) {
        int koff = step * 32 + (lane >> 4) * 8;
        sv8 af[2], bfr[4];
#pragma unroll
        for (int m = 0; m < 2; ++m)
            af[m] = *(const sv8*)(Q + (size_t)arow[m] * 1536 + koff);
#pragma unroll
        for (int n = 0; n < 4; ++n)
            bfr[n] = *(const sv8*)(Kb + (size_t)brow[n] * 1536 + koff);
#pragma unroll
        for (int m = 0; m < 2; ++m)
#pragma unroll
            for (int n = 0; n < 4; ++n)
                acc[m][n] = __builtin_amdgcn_mfma_f32_16x16x32_bf16(
                    af[m], bfr[n], acc[m][n], 0, 0, 0);
    }
    int r0 = (lane >> 4) * 4, c0 = lane & 15;
#pragma unroll
    for (int m = 0; m < 2; ++m)
#pragma unroll
        for (int n = 0; n < 4; ++n) {
            int jc = wn * 64 + n * 16 + c0;
#pragma unroll
            for (int j = 0; j < 4; ++j)
                sS[wm * 32 + m * 16 + r0 + j][jc] =
                    acc[m][n][j] * 0.04419417382415922f;  // 1/sqrt(512)
        }
    __syncthreads();

    // softmax: thread -> (q = tid>>2, quarter = tid&3)
    int q = tid >> 2, j0 = (tid & 3) * 32;
    float v[32];
    float mx = -1e30f;
    int jlo = q + 1;
    int jmin0 = 64 - t0;
    if (jmin0 > jlo) jlo = jmin0;
    int jhi = q + 64;
#pragma unroll
    for (int jj = 0; jj < 32; ++jj) {
        int j = j0 + jj;
        bool ok = (j >= jlo) && (j <= jhi);
        float s = ok ? sS[q][j] : -1e30f;
        v[jj] = s;
        mx = fmaxf(mx, s);
    }
    mx = fmaxf(mx, __shfl_xor(mx, 1));
    mx = fmaxf(mx, __shfl_xor(mx, 2));
    float sum = 0.f;
#pragma unroll
    for (int jj = 0; jj < 32; ++jj) {
        float e = (v[jj] > -1e29f) ? __expf(v[jj] - mx) : 0.f;
        v[jj] = e;
        sum += e;
    }
    sum += __shfl_xor(sum, 1);
    sum += __shfl_xor(sum, 2);
    float inv = 1.f / sum;
    short* dst = Pp + (size_t)tile * 8192 + q * 128 + j0;
#pragma unroll
    for (int k = 0; k < 4; ++k) {
        sv8 o;
#pragma unroll
        for (int e = 0; e < 8; ++e) o[e] = f2bf(v[k * 8 + e] * inv);
        *(sv8*)(dst + k * 8) = o;
    }
}

// ------------- PV: read[64 x 128-chunk] = P'[64x128] @ V'[128 x d] via Vt -------------
__global__ __launch_bounds__(256) void attn_pv(const short* __restrict__ Pp,
                                               const short* __restrict__ Vt,
                                               short* __restrict__ readb) {
    int tile = blockIdx.y, dchunk = blockIdx.x;  // 64 tiles x 4 d-chunks of 128
    int b = tile >> 5;
    int t0 = (tile & 31) * 64;
    int s0 = tile * 64;
    int tid = threadIdx.x, lane = tid & 63, wave = tid >> 6;
    int wm = wave >> 1, wn = wave & 1;

    f32x4 acc[2][4] = {};
    const short* Pbase = Pp + (size_t)tile * 8192;
#pragma unroll
    for (int ks = 0; ks < 4; ++ks) {
        int koff = ks * 32 + (lane >> 4) * 8;
        sv8 af[2], bfr[4];
#pragma unroll
        for (int m = 0; m < 2; ++m)
            af[m] = *(const sv8*)(Pbase + (wm * 32 + m * 16 + (lane & 15)) * 128 + koff);
#pragma unroll
        for (int n = 0; n < 4; ++n) {
            int d = dchunk * 128 + wn * 64 + n * 16 + (lane & 15);
            long off = (long)(b * 512 + d) * 2048 + (t0 - 64 + koff);  // <0 only where P'=0
            bfr[n] = *(const sv8*)(Vt + off);
        }
#pragma unroll
        for (int m = 0; m < 2; ++m)
#pragma unroll
            for (int n = 0; n < 4; ++n)
                acc[m][n] = __builtin_amdgcn_mfma_f32_16x16x32_bf16(
                    af[m], bfr[n], acc[m][n], 0, 0, 0);
    }
    int r0 = (lane >> 4) * 4, c0 = lane & 15;
#pragma unroll
    for (int m = 0; m < 2; ++m)
#pragma unroll
        for (int n = 0; n < 4; ++n) {
            int col = dchunk * 128 + wn * 64 + n * 16 + c0;
#pragma unroll
            for (int j = 0; j < 4; ++j) {
                int row = s0 + wm * 32 + m * 16 + r0 + j;
                readb[(size_t)row * 512 + col] = f2bf(acc[m][n][j]);
            }
        }
}

// ------------- LN(read) + LN(sence) + GeLU: one wave per row, sv8 loads -------------
__global__ __launch_bounds__(256) void ln_gelu(const short* __restrict__ readb,
                                               const short* __restrict__ Y,
                                               const float* __restrict__ gamma,
                                               const float* __restrict__ beta,
                                               float* __restrict__ out) {
    int row = blockIdx.x * 4 + (threadIdx.x >> 6);  // 4 waves = 4 rows per block
    int lane = threadIdx.x & 63;
    sv8 rv = *(const sv8*)(readb + (size_t)row * 512 + lane * 8);
    sv8 sv = *(const sv8*)(Y + (size_t)row * 1536 + 1024 + lane * 8);
    float rf[8], sf[8];
    float sr = 0.f, sr2 = 0.f, ss = 0.f, ss2 = 0.f;
#pragma unroll
    for (int e = 0; e < 8; ++e) {
        rf[e] = bf2f(rv[e]); sf[e] = bf2f(sv[e]);
        sr += rf[e]; sr2 += rf[e] * rf[e];
        ss += sf[e]; ss2 += sf[e] * sf[e];
    }
#pragma unroll
    for (int off = 32; off; off >>= 1) {
        sr += __shfl_xor(sr, off);
        sr2 += __shfl_xor(sr2, off);
        ss += __shfl_xor(ss, off);
        ss2 += __shfl_xor(ss2, off);
    }
    float mu_r = sr * (1.f / 512.f);
    float is_r = rsqrtf(sr2 * (1.f / 512.f) - mu_r * mu_r + 1e-5f);
    float mu_s = ss * (1.f / 512.f);
    float is_s = rsqrtf(ss2 * (1.f / 512.f) - mu_s * mu_s + 1e-5f);

    float4 ga = ((const float4*)gamma)[lane * 2];
    float4 gb = ((const float4*)gamma)[lane * 2 + 1];
    float4 ba = ((const float4*)beta)[lane * 2];
    float4 bb = ((const float4*)beta)[lane * 2 + 1];
    float g[8] = {ga.x, ga.y, ga.z, ga.w, gb.x, gb.y, gb.z, gb.w};
    float be[8] = {ba.x, ba.y, ba.z, ba.w, bb.x, bb.y, bb.z, bb.w};

    float y[8];
#pragma unroll
    for (int e = 0; e < 8; ++e) {
        float xv = (rf[e] - mu_r) * is_r * g[e] + be[e] +
                   (sf[e] - mu_s) * is_s * g[e] + be[e];
        y[e] = 0.5f * xv * (1.f + erff(xv * 0.70710678118654752f));
    }
    float* o = out + (size_t)row * 512 + lane * 8;
    ((float4*)o)[0] = make_float4(y[0], y[1], y[2], y[3]);
    ((float4*)o)[1] = make_float4(y[4], y[5], y[6], y[7]);
}

extern "C" void kernel_launch(void* const* d_in, const int* in_sizes, int n_in,
                              void* d_out, int out_size, void* d_ws, size_t ws_size,
                              hipStream_t stream) {
    const float* x  = (const float*)d_in[0];
    const float* Wq = (const float*)d_in[1];
    const float* bq = (const float*)d_in[2];
    const float* Wk = (const float*)d_in[3];
    const float* bk = (const float*)d_in[4];
    const float* Wv = (const float*)d_in[5];
    const float* bv = (const float*)d_in[6];
    const float* Wo = (const float*)d_in[7];
    const float* bo = (const float*)d_in[8];
    const float* Wr = (const float*)d_in[9];
    const float* br = (const float*)d_in[10];
    const float* gamma = (const float*)d_in[11];
    const float* beta  = (const float*)d_in[12];

    char* ws = (char*)d_ws;
    short* xb    = (short*)(ws + OFF_XB);
    short* wt    = (short*)(ws + OFF_WT);
    float* ball  = (float*)(ws + OFF_BIAS);
    short* Y     = (short*)(ws + OFF_Y);
    short* vtb   = (short*)(ws + OFF_VT);
    short* readb = (short*)(ws + OFF_READ);
    short* Pp    = (short*)(ws + OFF_PP);
    short* wvraw = (short*)(ws + OFF_WVRAW);

    prep_all<<<dim3(16, 16, 6), 256, 0, stream>>>(x, Wq, Wk, Wv, Wr, Wo,
                                                  bq, bk, bv, br, bo, xb, wt, wvraw, ball);

    // Wvo^T = (Wv@Wo)^T into wt slot 2: C[m][n] = Wo^T[m][:] . Wv[n][:] = Wvo[n][m]
    gemm_bt<2><<<dim3(4, 4), 256, 0, stream>>>(wt + (size_t)4 * 512 * 512, wvraw,
                                               nullptr, wt + (size_t)2 * 512 * 512,
                                               512, nullptr);

    // one launch: Y=[q|k|sence] plus V't (v' cols, transposed via operand swap)
    gemm_bt<1><<<dim3(16, 32), 256, 0, stream>>>(xb, wt, ball, Y, 1536, vtb);

    attn_scores<<<64, 256, 0, stream>>>(Y, Pp);
    attn_pv<<<dim3(4, 64), 256, 0, stream>>>(Pp, vtb, readb);  // = read directly

    ln_gelu<<<1024, 256, 0, stream>>>(readb, Y, gamma, beta, (float*)d_out);
}